// Round 3
// baseline (346.549 us; speedup 1.0000x reference)
//
#include <hip/hip_runtime.h>
#include <cmath>

#define N_TOK 8192
#define DIM   384
#define NEXP  8
#define HID   1536
#define OUTD  384
#define CAP_MT 80     // 32-row tile capacity per expert (2560 tokens >> 2048+12sigma)
#define CAP_TB 20     // 128-row block capacity per expert
#define HPITCH 136    // shorts; 272B row pitch: 16B-aligned ds_read_b128, 4-way bank alias (1.58x, acceptable)

typedef __attribute__((ext_vector_type(8)))  __bf16 bf16x8;
typedef __attribute__((ext_vector_type(16))) float  f32x16;

__device__ __forceinline__ unsigned short f2bf(float f) {
    unsigned u = __float_as_uint(f);
    u += 0x7FFF + ((u >> 16) & 1);          // round-to-nearest-even
    return (unsigned short)(u >> 16);
}

__device__ __forceinline__ float gelu_exact(float x) {
    return 0.5f * x * (1.0f + erff(x * 0.70710678118654752f));
}

// ---------------------------------------------------------------- init
__global__ void init_kernel(float* __restrict__ out, int* __restrict__ cnt) {
    int gid = blockIdx.x * blockDim.x + threadIdx.x;
    if (gid < NEXP) cnt[gid] = 0;
    float4* o4 = (float4*)out;
    const int n4 = N_TOK * OUTD / 4;
    for (int i = gid; i < n4; i += gridDim.x * blockDim.x)
        o4[i] = make_float4(0.f, 0.f, 0.f, 0.f);
}

// ------------------------------------------------- W[e][K][N] fp32 -> B-fragment order bf16
// dst[((e*NT + nt)*KT + kt)*64 + l][j] = bf16(src[e][kt*16 + (l>>5)*8 + j][nt*32 + (l&31)])
__global__ void swizzle_kernel(const float* __restrict__ src, unsigned short* __restrict__ dst,
                               int K, int N, int NT, int KT) {
    int gid = blockIdx.x * blockDim.x + threadIdx.x;
    int total = NEXP * NT * KT * 64;
    if (gid >= total) return;
    int l  = gid & 63;
    int kt = (gid >> 6) % KT;
    int nt = ((gid >> 6) / KT) % NT;
    int e  = gid / (64 * KT * NT);
    const float* s = src + ((size_t)e * K + kt * 16 + (l >> 5) * 8) * N + nt * 32 + (l & 31);
    unsigned short r[8];
    #pragma unroll
    for (int j = 0; j < 8; ++j) r[j] = f2bf(s[(size_t)j * N]);
    *(uint4*)(dst + (size_t)gid * 8) = *(uint4*)r;
}

// ---------------------------------------------------------------- router (LDS-aggregated)
__global__ void router_kernel(const float* __restrict__ x, const float* __restrict__ Wg,
                              const float* __restrict__ bg, int* __restrict__ cnt,
                              int* __restrict__ btok, float* __restrict__ bgate) {
    __shared__ float WgL[DIM * NEXP];
    __shared__ int lcnt[NEXP];
    __shared__ int lbase[NEXP];
    int tid = threadIdx.x;
    for (int i = tid; i < DIM * NEXP; i += 256) WgL[i] = Wg[i];
    if (tid < NEXP) lcnt[tid] = 0;
    __syncthreads();

    int t = blockIdx.x * 256 + tid;
    float lg[NEXP];
    #pragma unroll
    for (int e = 0; e < NEXP; ++e) lg[e] = bg[e];

    const float4* xr = (const float4*)(x + (size_t)t * DIM);
    for (int d4 = 0; d4 < DIM / 4; ++d4) {
        float4 v = xr[d4];
        const float* wrow = &WgL[d4 * 4 * NEXP];
        #pragma unroll
        for (int e = 0; e < NEXP; ++e)
            lg[e] += v.x * wrow[e] + v.y * wrow[NEXP + e]
                   + v.z * wrow[2 * NEXP + e] + v.w * wrow[3 * NEXP + e];
    }

    float v0 = -INFINITY, v1 = -INFINITY; int i0 = 0, i1 = 0;
    #pragma unroll
    for (int e = 0; e < NEXP; ++e) {
        float v = lg[e];
        if (v > v0)      { v1 = v0; i1 = i0; v0 = v; i0 = e; }
        else if (v > v1) { v1 = v;  i1 = e; }
    }
    float e1 = expf(v1 - v0);
    float g0 = 1.f / (1.f + e1);
    float g1 = e1  / (1.f + e1);

    int p0 = atomicAdd(&lcnt[i0], 1);
    int p1 = atomicAdd(&lcnt[i1], 1);
    __syncthreads();
    if (tid < NEXP) lbase[tid] = atomicAdd(&cnt[tid], lcnt[tid]);
    __syncthreads();
    int o0 = lbase[i0] + p0, o1 = lbase[i1] + p1;
    btok[i0 * N_TOK + o0]  = t;  bgate[i0 * N_TOK + o0] = g0;
    btok[i1 * N_TOK + o1]  = t;  bgate[i1 * N_TOK + o1] = g1;
}

// ------------------------------------------ gather x rows into A-fragment order (bf16)
// xg[((e*CAP_MT + mt)*24 + kt)*64 + kh*32 + m][j] = bf16(x[tok(e,mt*32+m)][kt*16 + kh*8 + j])
__global__ void gather_kernel(const float* __restrict__ x, const int* __restrict__ cnt,
                              const int* __restrict__ btok, unsigned short* __restrict__ xg) {
    int mt = blockIdx.x, e = blockIdx.y;
    int cntE = cnt[e];
    if (mt * 32 >= cntE) return;
    int tid = threadIdx.x;                 // 256
    int m = tid & 31, kt0 = tid >> 5;      // 32 x 8
    int pos = mt * 32 + m;
    int idx = (pos < cntE) ? pos : cntE - 1;   // clamp pad rows (masked later)
    int tok = btok[e * N_TOK + idx];
    const float* xr = x + (size_t)tok * DIM;
    #pragma unroll
    for (int kk = 0; kk < 3; ++kk) {
        int kt = kt0 + kk * 8;
        #pragma unroll
        for (int kh = 0; kh < 2; ++kh) {
            float4 v0 = *(const float4*)(xr + kt * 16 + kh * 8);
            float4 v1 = *(const float4*)(xr + kt * 16 + kh * 8 + 4);
            unsigned short rr[8];
            rr[0] = f2bf(v0.x); rr[1] = f2bf(v0.y); rr[2] = f2bf(v0.z); rr[3] = f2bf(v0.w);
            rr[4] = f2bf(v1.x); rr[5] = f2bf(v1.y); rr[6] = f2bf(v1.z); rr[7] = f2bf(v1.w);
            *(uint4*)(xg + (size_t)(((e * CAP_MT + mt) * 24 + kt) * 64 + kh * 32 + m) * 8) =
                *(uint4*)rr;
        }
    }
}

// ---------------------------------------------------------------- fused expert MLP
// 512 threads (8 waves). Block = (expert e = L&7 [XCD-pinned], hid-slice hs (384 cols),
// token-block tb (128 rows)). 3 chunks of 128 hid cols:
//   GEMM1: wave (ni=w&3, mh=w>>2): 64 rows x 32 cols, K=384, A from global xg frags,
//          B from global w1s frags (all coalesced 1KB dwordx4). GELU -> h_lds.
//   GEMM2: wave (oj=w&3, mh2=w>>2): 64 rows x 96 cols, K=128 chunk, A from h_lds.
// Epilogue: atomic gate-weighted add into out; b2 added by hs==0 blocks only.
__global__ __launch_bounds__(512, 2) void expert_kernel(
        const unsigned short* __restrict__ xg,  const unsigned short* __restrict__ w1s,
        const unsigned short* __restrict__ w2s, const float* __restrict__ b1,
        const float* __restrict__ b2,           const int* __restrict__ cnt,
        const int* __restrict__ btok,           const float* __restrict__ bgate,
        float* __restrict__ out) {
    int L  = blockIdx.x;
    int e  = L & 7;               // XCD-pinned: block L runs on XCD L%8
    int r  = L >> 3;              // 0..79
    int hs = r & 3;               // hid-slice (384 cols)
    int tb = r >> 2;              // 0..19 token-block
    int cntE = cnt[e];
    if (tb * 128 >= cntE) return;
    int nvalid = min(128, cntE - tb * 128);

    __shared__ unsigned short h_lds[128 * HPITCH];   // 34.8 KB
    __shared__ int   tokL[128];
    __shared__ float gateL[128];

    int tid = threadIdx.x;
    if (tid < 128) {
        int idx = tb * 128 + ((tid < nvalid) ? tid : 0);
        tokL[tid]  = btok[e * N_TOK + idx];
        gateL[tid] = bgate[e * N_TOK + idx];
    }

    int wave = tid >> 6, lane = tid & 63;
    int m31 = lane & 31, kh = lane >> 5;
    int ni = wave & 3, mh = wave >> 2;    // GEMM1 roles
    int oj = ni, mh2 = mh;                // GEMM2 roles (same split)

    f32x16 acc2[6];
    #pragma unroll
    for (int i = 0; i < 6; ++i)
        acc2[i] = (f32x16){0.f,0.f,0.f,0.f,0.f,0.f,0.f,0.f,0.f,0.f,0.f,0.f,0.f,0.f,0.f,0.f};

    const unsigned short* ap0 = xg + ((size_t)(e * CAP_MT + tb * 4 + mh * 2) * 24) * 512 + lane * 8;
    const unsigned short* ap1 = ap0 + 24 * 512;
    const unsigned short* hb  = &h_lds[(mh2 * 64 + m31) * HPITCH + kh * 8];

    __syncthreads();   // tokL/gateL visible (also before first h_lds use)

    for (int hc = 0; hc < 3; ++hc) {
        // ---- GEMM1: 64x32 per wave, K=384
        f32x16 acc1[2];
        acc1[0] = (f32x16){0.f,0.f,0.f,0.f,0.f,0.f,0.f,0.f,0.f,0.f,0.f,0.f,0.f,0.f,0.f,0.f};
        acc1[1] = acc1[0];
        const unsigned short* wp =
            w1s + ((size_t)(e * 48 + hs * 12 + hc * 4 + ni) * 24) * 512 + lane * 8;
        #pragma unroll 8
        for (int kt = 0; kt < 24; ++kt) {
            bf16x8 b  = *(const bf16x8*)(wp  + kt * 512);
            bf16x8 a0 = *(const bf16x8*)(ap0 + kt * 512);
            bf16x8 a1 = *(const bf16x8*)(ap1 + kt * 512);
            acc1[0] = __builtin_amdgcn_mfma_f32_32x32x16_bf16(a0, b, acc1[0], 0, 0, 0);
            acc1[1] = __builtin_amdgcn_mfma_f32_32x32x16_bf16(a1, b, acc1[1], 0, 0, 0);
        }
        // ---- bias + exact gelu -> h_lds
        int colL = ni * 32 + m31;
        float b1v = b1[e * HID + hs * 384 + hc * 128 + colL];
        #pragma unroll
        for (int t = 0; t < 2; ++t)
            #pragma unroll
            for (int rr = 0; rr < 16; ++rr) {
                int row = mh * 64 + t * 32 + (rr & 3) + 8 * (rr >> 2) + 4 * kh;
                h_lds[row * HPITCH + colL] = f2bf(gelu_exact(acc1[t][rr] + b1v));
            }
        __syncthreads();
        // ---- GEMM2: 64x96 per wave, K=128 chunk, accumulate across hc
        #pragma unroll
        for (int ks = 0; ks < 8; ++ks) {
            bf16x8 a0 = *(const bf16x8*)(hb + ks * 16);
            bf16x8 a1 = *(const bf16x8*)(hb + 32 * HPITCH + ks * 16);
            #pragma unroll
            for (int o = 0; o < 3; ++o) {
                const unsigned short* w2p =
                    w2s + ((size_t)(e * 12 + oj * 3 + o) * 96 + hs * 24 + hc * 8 + ks) * 512 + lane * 8;
                bf16x8 b = *(const bf16x8*)w2p;
                acc2[o * 2 + 0] = __builtin_amdgcn_mfma_f32_32x32x16_bf16(a0, b, acc2[o * 2 + 0], 0, 0, 0);
                acc2[o * 2 + 1] = __builtin_amdgcn_mfma_f32_32x32x16_bf16(a1, b, acc2[o * 2 + 1], 0, 0, 0);
            }
        }
        __syncthreads();   // h_lds reused next chunk
    }

    // ---- epilogue: out[tok][o] += gate * (y [+ b2 if hs==0])
    #pragma unroll
    for (int o = 0; o < 3; ++o) {
        int ocol = (oj * 3 + o) * 32 + m31;
        float b2v = (hs == 0) ? b2[e * OUTD + ocol] : 0.f;
        #pragma unroll
        for (int t = 0; t < 2; ++t)
            #pragma unroll
            for (int rr = 0; rr < 16; ++rr) {
                int row = mh2 * 64 + t * 32 + (rr & 3) + 8 * (rr >> 2) + 4 * kh;
                if (row < nvalid) {
                    float val = (acc2[o * 2 + t][rr] + b2v) * gateL[row];
                    unsafeAtomicAdd(&out[(size_t)tokL[row] * OUTD + ocol], val);
                }
            }
    }
}

// ---------------------------------------------------------------- launch
extern "C" void kernel_launch(void* const* d_in, const int* in_sizes, int n_in,
                              void* d_out, int out_size, void* d_ws, size_t ws_size,
                              hipStream_t stream) {
    const float* x  = (const float*)d_in[0];
    const float* Wg = (const float*)d_in[1];
    const float* bg = (const float*)d_in[2];
    const float* W1 = (const float*)d_in[3];
    const float* b1 = (const float*)d_in[4];
    const float* W2 = (const float*)d_in[5];
    const float* b2 = (const float*)d_in[6];
    float* out = (float*)d_out;

    char* ws = (char*)d_ws;
    int*            cnt   = (int*)ws;                          // 32 B
    int*            btok  = (int*)(ws + 256);                  // 256 KB
    float*          bgate = (float*)(ws + 262400);             // 256 KB
    unsigned short* w1s   = (unsigned short*)(ws + 524544);    // 9.44 MB
    unsigned short* w2s   = (unsigned short*)(ws + 9961728);   // 9.44 MB
    unsigned short* xg    = (unsigned short*)(ws + 19398912);  // 15.73 MB -> end ~33.5 MB

    hipLaunchKernelGGL(init_kernel, dim3(1024), dim3(256), 0, stream, out, cnt);
    // W1: K=DIM, N=HID -> NT=48, KT=24 ; W2: K=HID, N=OUTD -> NT=12, KT=96
    hipLaunchKernelGGL(swizzle_kernel, dim3(NEXP * 48 * 24 * 64 / 256), dim3(256), 0, stream,
                       W1, w1s, DIM, HID, 48, 24);
    hipLaunchKernelGGL(swizzle_kernel, dim3(NEXP * 12 * 96 * 64 / 256), dim3(256), 0, stream,
                       W2, w2s, HID, OUTD, 12, 96);
    hipLaunchKernelGGL(router_kernel, dim3(N_TOK / 256), dim3(256), 0, stream,
                       x, Wg, bg, cnt, btok, bgate);
    hipLaunchKernelGGL(gather_kernel, dim3(CAP_MT, NEXP), dim3(256), 0, stream,
                       x, cnt, btok, xg);
    hipLaunchKernelGGL(expert_kernel, dim3(NEXP * 4 * CAP_TB), dim3(512), 0, stream,
                       xg, w1s, w2s, b1, b2, cnt, btok, bgate, out);
}

// Round 4
// 304.309 us; speedup vs baseline: 1.1388x; 1.1388x over previous
//
#include <hip/hip_runtime.h>
#include <cmath>

#define N_TOK 8192
#define DIM   384
#define NEXP  8
#define HID   1536
#define OUTD  384
#define CAP_MT 72        // 32-row gather tiles per expert (2304 tokens, mean 2048, >6 sigma)
#define CAP_TOK 2304
#define CAP_TB 18        // 128-row expert blocks per expert
#define HPITCH 136       // h_lds row pitch in shorts (272B): 16B-aligned, measured 0 conflicts (R3)

typedef __attribute__((ext_vector_type(8)))  __bf16 bf16x8;
typedef __attribute__((ext_vector_type(16))) float  f32x16;

__device__ __forceinline__ unsigned short f2bf(float f) {
    unsigned u = __float_as_uint(f);
    u += 0x7FFF + ((u >> 16) & 1);          // round-to-nearest-even
    return (unsigned short)(u >> 16);
}

__device__ __forceinline__ float gelu_exact(float x) {
    return 0.5f * x * (1.0f + erff(x * 0.70710678118654752f));
}

// async global->LDS, 16B per lane; LDS dest = wave-uniform tile base (HW adds lane*16)
__device__ __forceinline__ void cp16(const unsigned short* g, unsigned short* l) {
    __builtin_amdgcn_global_load_lds(
        (const __attribute__((address_space(1))) unsigned int*)g,
        (__attribute__((address_space(3))) unsigned int*)l, 16, 0, 0);
}

// ---------------------------------------------------------------- init (zero yp + cnt)
__global__ void init_kernel(float* __restrict__ yp, int* __restrict__ cnt) {
    int gid = blockIdx.x * blockDim.x + threadIdx.x;
    if (gid < NEXP) cnt[gid] = 0;
    float4* p = (float4*)yp;
    const int n4 = NEXP * CAP_TOK * OUTD / 4;
    for (int i = gid; i < n4; i += gridDim.x * blockDim.x)
        p[i] = make_float4(0.f, 0.f, 0.f, 0.f);
}

// ------------------------------------------------- W[e][K][N] fp32 -> B-fragment order bf16
// dst[((e*NT + nt)*KT + kt)*64 + l][j] = bf16(src[e][kt*16 + (l>>5)*8 + j][nt*32 + (l&31)])
__global__ void swizzle_kernel(const float* __restrict__ src, unsigned short* __restrict__ dst,
                               int K, int N, int NT, int KT) {
    int gid = blockIdx.x * blockDim.x + threadIdx.x;
    int total = NEXP * NT * KT * 64;
    if (gid >= total) return;
    int l  = gid & 63;
    int kt = (gid >> 6) % KT;
    int nt = ((gid >> 6) / KT) % NT;
    int e  = gid / (64 * KT * NT);
    const float* s = src + ((size_t)e * K + kt * 16 + (l >> 5) * 8) * N + nt * 32 + (l & 31);
    unsigned short r[8];
    #pragma unroll
    for (int j = 0; j < 8; ++j) r[j] = f2bf(s[(size_t)j * N]);
    *(uint4*)(dst + (size_t)gid * 8) = *(uint4*)r;
}

// ---------------------------------------------------------------- router
__global__ void router_kernel(const float* __restrict__ x, const float* __restrict__ Wg,
                              const float* __restrict__ bg, int* __restrict__ cnt,
                              int* __restrict__ btok, int* __restrict__ tokmap,
                              float* __restrict__ gmap) {
    __shared__ float WgL[DIM * NEXP];
    __shared__ int lcnt[NEXP];
    __shared__ int lbase[NEXP];
    int tid = threadIdx.x;
    for (int i = tid; i < DIM * NEXP; i += 256) WgL[i] = Wg[i];
    if (tid < NEXP) lcnt[tid] = 0;
    __syncthreads();

    int t = blockIdx.x * 256 + tid;
    float lg[NEXP];
    #pragma unroll
    for (int e = 0; e < NEXP; ++e) lg[e] = bg[e];

    const float4* xr = (const float4*)(x + (size_t)t * DIM);
    for (int d4 = 0; d4 < DIM / 4; ++d4) {
        float4 v = xr[d4];
        const float* wrow = &WgL[d4 * 4 * NEXP];
        #pragma unroll
        for (int e = 0; e < NEXP; ++e)
            lg[e] += v.x * wrow[e] + v.y * wrow[NEXP + e]
                   + v.z * wrow[2 * NEXP + e] + v.w * wrow[3 * NEXP + e];
    }

    float v0 = -INFINITY, v1 = -INFINITY; int i0 = 0, i1 = 0;
    #pragma unroll
    for (int e = 0; e < NEXP; ++e) {
        float v = lg[e];
        if (v > v0)      { v1 = v0; i1 = i0; v0 = v; i0 = e; }
        else if (v > v1) { v1 = v;  i1 = e; }
    }
    float e1 = expf(v1 - v0);
    float g0 = 1.f / (1.f + e1);
    float g1 = e1  / (1.f + e1);

    int p0 = atomicAdd(&lcnt[i0], 1);
    int p1 = atomicAdd(&lcnt[i1], 1);
    __syncthreads();
    if (tid < NEXP) lbase[tid] = atomicAdd(&cnt[tid], lcnt[tid]);
    __syncthreads();
    int o0 = lbase[i0] + p0, o1 = lbase[i1] + p1;
    btok[i0 * N_TOK + o0] = t;
    btok[i1 * N_TOK + o1] = t;
    ((int4*)tokmap)[t] = make_int4(i0, o0, i1, o1);
    ((float2*)gmap)[t] = make_float2(g0, g1);
}

// ------------------------------------------ gather x rows into A-fragment order (bf16)
__global__ void gather_kernel(const float* __restrict__ x, const int* __restrict__ cnt,
                              const int* __restrict__ btok, unsigned short* __restrict__ xg) {
    int mt = blockIdx.x, e = blockIdx.y;
    int cntE = cnt[e];
    if (mt * 32 >= cntE) return;
    int tid = threadIdx.x;                 // 256
    int m = tid & 31, kt0 = tid >> 5;      // 32 x 8
    int pos = mt * 32 + m;
    int idx = (pos < cntE) ? pos : cntE - 1;   // clamp pad rows (masked later)
    int tok = btok[e * N_TOK + idx];
    const float* xr = x + (size_t)tok * DIM;
    #pragma unroll
    for (int kk = 0; kk < 3; ++kk) {
        int kt = kt0 + kk * 8;
        #pragma unroll
        for (int kh = 0; kh < 2; ++kh) {
            float4 v0 = *(const float4*)(xr + kt * 16 + kh * 8);
            float4 v1 = *(const float4*)(xr + kt * 16 + kh * 8 + 4);
            unsigned short rr[8];
            rr[0] = f2bf(v0.x); rr[1] = f2bf(v0.y); rr[2] = f2bf(v0.z); rr[3] = f2bf(v0.w);
            rr[4] = f2bf(v1.x); rr[5] = f2bf(v1.y); rr[6] = f2bf(v1.z); rr[7] = f2bf(v1.w);
            *(uint4*)(xg + (size_t)(((e * CAP_MT + mt) * 24 + kt) * 64 + kh * 32 + m) * 8) =
                *(uint4*)rr;
        }
    }
}

// ---------------------------------------------------------------- fused expert MLP
// 512 thr (8 waves). Block = (e = L&7 [XCD-pin], hs quarter of HID, tb: 128 tokens).
// All fragments staged via async global_load_lds into 32KB LDS (tiles are 1KB, frag order),
// consumed with conflict-free ds_read_b128. m97 2-barrier structure.
// Partial outputs atomically accumulated into yp[e][pos][384] (same-XCD atomics only).
__global__ __launch_bounds__(512, 2) void expert_kernel(
        const unsigned short* __restrict__ xg,  const unsigned short* __restrict__ w1s,
        const unsigned short* __restrict__ w2s, const float* __restrict__ b1,
        const int* __restrict__ cnt,            float* __restrict__ yp) {
    int L  = blockIdx.x;
    int e  = L & 7;
    int r  = L >> 3;
    int hs = r & 3;               // hid-slice (384 cols)
    int tb = r >> 2;              // 128-token block
    int cntE = cnt[e];
    if (tb * 128 >= cntE) return;

    __shared__ unsigned short stg[16384];            // 32 KB stage buffer (32 x 1KB tiles)
    __shared__ unsigned short h_lds[128 * HPITCH];   // 34.8 KB

    int tid  = threadIdx.x;
    int wave = tid >> 6, lane = tid & 63;
    int m31 = lane & 31, kh = lane >> 5;
    int mh = wave >> 2, ni = wave & 3;    // GEMM1: mh = row-half (64 rows), ni = 32-col tile
    int oj = ni;                          // GEMM2: oj = 96-col out group, same mh

    f32x16 acc2[6];
    #pragma unroll
    for (int i = 0; i < 6; ++i)
        acc2[i] = (f32x16){0.f,0.f,0.f,0.f,0.f,0.f,0.f,0.f,0.f,0.f,0.f,0.f,0.f,0.f,0.f,0.f};

    const unsigned short* xg_e = xg + ((size_t)(e * CAP_MT + tb * 4) * 24) * 512;
    const unsigned short* w1_e = w1s + ((size_t)(e * 48 + hs * 12) * 24) * 512;

    for (int hc = 0; hc < 3; ++hc) {
        // ================= GEMM1: h[128][128] = x[128][384] @ W1 chunk =================
        f32x16 acc1[2];
        acc1[0] = (f32x16){0.f,0.f,0.f,0.f,0.f,0.f,0.f,0.f,0.f,0.f,0.f,0.f,0.f,0.f,0.f,0.f};
        acc1[1] = acc1[0];
        for (int ktg = 0; ktg < 6; ++ktg) {          // 4 kt (=64 K) per group
            __syncthreads();                          // stg free (prev consume done)
            #pragma unroll
            for (int i = 0; i < 4; ++i) {             // 32 tiles: 16 x-tiles + 16 W1-tiles
                int tl = i * 8 + wave;
                const unsigned short* src;
                if (tl < 16) {                        // x tile: [mt 0..3][kt 0..3]
                    int mt = tl >> 2, kt = tl & 3;
                    src = xg_e + ((size_t)mt * 24 + ktg * 4 + kt) * 512;
                } else {                              // W1 tile: [ni 0..3][kt 0..3]
                    int t2 = tl - 16;
                    int nn = t2 >> 2, kt = t2 & 3;
                    src = w1_e + ((size_t)(hc * 4 + nn) * 24 + ktg * 4 + kt) * 512;
                }
                cp16(src + lane * 8, &stg[tl * 512]);
            }
            __syncthreads();                          // drain vmcnt: staged data visible
            #pragma unroll
            for (int kt = 0; kt < 4; ++kt) {
                bf16x8 b  = *(const bf16x8*)&stg[(16 + ni * 4 + kt) * 512 + lane * 8];
                bf16x8 a0 = *(const bf16x8*)&stg[((mh * 2 + 0) * 4 + kt) * 512 + lane * 8];
                bf16x8 a1 = *(const bf16x8*)&stg[((mh * 2 + 1) * 4 + kt) * 512 + lane * 8];
                acc1[0] = __builtin_amdgcn_mfma_f32_32x32x16_bf16(a0, b, acc1[0], 0, 0, 0);
                acc1[1] = __builtin_amdgcn_mfma_f32_32x32x16_bf16(a1, b, acc1[1], 0, 0, 0);
            }
        }
        // ---- bias + exact gelu -> h_lds (C-layout rows, pitch 136)
        int colL = ni * 32 + m31;
        float b1v = b1[e * HID + hs * 384 + hc * 128 + colL];
        #pragma unroll
        for (int s = 0; s < 2; ++s)
            #pragma unroll
            for (int rr = 0; rr < 16; ++rr) {
                int row = mh * 64 + s * 32 + (rr & 3) + 8 * (rr >> 2) + 4 * kh;
                h_lds[row * HPITCH + colL] = f2bf(gelu_exact(acc1[s][rr] + b1v));
            }
        // ================= GEMM2: y[128][384] += h[128][128] @ W2 chunk ================
        for (int ksg = 0; ksg < 4; ++ksg) {          // 2 ks (=32 K) per group
            __syncthreads();                          // h visible (ksg=0) + stg free
            #pragma unroll
            for (int i = 0; i < 3; ++i) {             // 24 W2 tiles: [nc 0..11][j 0..1]
                int tl = i * 8 + wave;
                int nc = tl >> 1, j = tl & 1;
                const unsigned short* src =
                    w2s + ((size_t)(e * 12 + nc) * 96 + hs * 24 + hc * 8 + ksg * 2 + j) * 512;
                cp16(src + lane * 8, &stg[tl * 512]);
            }
            __syncthreads();
            #pragma unroll
            for (int j = 0; j < 2; ++j) {
                int kcol = (ksg * 2 + j) * 16 + kh * 8;
                bf16x8 a0 = *(const bf16x8*)&h_lds[(mh * 64 +  0 + m31) * HPITCH + kcol];
                bf16x8 a1 = *(const bf16x8*)&h_lds[(mh * 64 + 32 + m31) * HPITCH + kcol];
                #pragma unroll
                for (int o = 0; o < 3; ++o) {
                    bf16x8 b = *(const bf16x8*)&stg[((oj * 3 + o) * 2 + j) * 512 + lane * 8];
                    acc2[o * 2 + 0] = __builtin_amdgcn_mfma_f32_32x32x16_bf16(a0, b, acc2[o * 2 + 0], 0, 0, 0);
                    acc2[o * 2 + 1] = __builtin_amdgcn_mfma_f32_32x32x16_bf16(a1, b, acc2[o * 2 + 1], 0, 0, 0);
                }
            }
        }
    }

    // ---- epilogue: yp[e][pos][col] += y  (4 hs-blocks, all on XCD e -> L2-local atomics)
    #pragma unroll
    for (int o = 0; o < 3; ++o) {
        int col = (oj * 3 + o) * 32 + m31;
        #pragma unroll
        for (int s = 0; s < 2; ++s)
            #pragma unroll
            for (int rr = 0; rr < 16; ++rr) {
                int row = mh * 64 + s * 32 + (rr & 3) + 8 * (rr >> 2) + 4 * kh;
                int pos = tb * 128 + row;
                if (pos < cntE)
                    unsafeAtomicAdd(&yp[((size_t)e * CAP_TOK + pos) * OUTD + col],
                                    acc2[o * 2 + s][rr]);
            }
    }
}

// ---------------------------------------------------------------- reduce: out = sum_k g_k*(yp_k + b2[e_k])
__global__ void reduce_kernel(const float* __restrict__ yp, const int* __restrict__ tokmap,
                              const float* __restrict__ gmap, const float* __restrict__ b2,
                              float* __restrict__ out) {
    int gid = blockIdx.x * 256 + threadIdx.x;      // N_TOK * 96 threads
    int t = gid / 96, q = gid - t * 96;
    int4   tm = ((const int4*)tokmap)[t];
    float2 g  = ((const float2*)gmap)[t];
    float4 y0 = *(const float4*)&yp[((size_t)tm.x * CAP_TOK + tm.y) * OUTD + q * 4];
    float4 y1 = *(const float4*)&yp[((size_t)tm.z * CAP_TOK + tm.w) * OUTD + q * 4];
    float4 c0 = *(const float4*)&b2[tm.x * OUTD + q * 4];
    float4 c1 = *(const float4*)&b2[tm.z * OUTD + q * 4];
    float4 rv;
    rv.x = g.x * (y0.x + c0.x) + g.y * (y1.x + c1.x);
    rv.y = g.x * (y0.y + c0.y) + g.y * (y1.y + c1.y);
    rv.z = g.x * (y0.z + c0.z) + g.y * (y1.z + c1.z);
    rv.w = g.x * (y0.w + c0.w) + g.y * (y1.w + c1.w);
    *(float4*)&out[(size_t)t * OUTD + q * 4] = rv;
}

// ---------------------------------------------------------------- launch
extern "C" void kernel_launch(void* const* d_in, const int* in_sizes, int n_in,
                              void* d_out, int out_size, void* d_ws, size_t ws_size,
                              hipStream_t stream) {
    const float* x  = (const float*)d_in[0];
    const float* Wg = (const float*)d_in[1];
    const float* bg = (const float*)d_in[2];
    const float* W1 = (const float*)d_in[3];
    const float* b1 = (const float*)d_in[4];
    const float* W2 = (const float*)d_in[5];
    const float* b2 = (const float*)d_in[6];
    float* out = (float*)d_out;

    char* ws = (char*)d_ws;                                    // all offsets 1KB-aligned
    int*            cnt    = (int*)ws;                         // 32 B
    int*            btok   = (int*)(ws + 1024);                // 256 KB
    int*            tokmap = (int*)(ws + 263168);              // 128 KB
    float*          gmap   = (float*)(ws + 394240);            // 64 KB
    unsigned short* xg     = (unsigned short*)(ws + 459776);   // 13.5 MB
    unsigned short* w1s    = (unsigned short*)(ws + 14615552); // 9.44 MB
    unsigned short* w2s    = (unsigned short*)(ws + 24052736); // 9.44 MB
    float*          yp     = (float*)(ws + 33489920);          // 28.3 MB -> end ~59 MB

    hipLaunchKernelGGL(init_kernel, dim3(1024), dim3(256), 0, stream, yp, cnt);
    // W1: K=DIM, N=HID -> NT=48, KT=24 ; W2: K=HID, N=OUTD -> NT=12, KT=96
    hipLaunchKernelGGL(swizzle_kernel, dim3(NEXP * 48 * 24 * 64 / 256), dim3(256), 0, stream,
                       W1, w1s, DIM, HID, 48, 24);
    hipLaunchKernelGGL(swizzle_kernel, dim3(NEXP * 12 * 96 * 64 / 256), dim3(256), 0, stream,
                       W2, w2s, HID, OUTD, 12, 96);
    hipLaunchKernelGGL(router_kernel, dim3(N_TOK / 256), dim3(256), 0, stream,
                       x, Wg, bg, cnt, btok, tokmap, gmap);
    hipLaunchKernelGGL(gather_kernel, dim3(CAP_MT, NEXP), dim3(256), 0, stream,
                       x, cnt, btok, xg);
    hipLaunchKernelGGL(expert_kernel, dim3(NEXP * 4 * CAP_TB), dim3(512), 0, stream,
                       xg, w1s, w2s, b1, cnt, yp);
    hipLaunchKernelGGL(reduce_kernel, dim3(N_TOK * 96 / 256), dim3(256), 0, stream,
                       yp, tokmap, gmap, b2, out);
}

// Round 5
// 267.257 us; speedup vs baseline: 1.2967x; 1.1386x over previous
//
#include <hip/hip_runtime.h>
#include <cmath>

#define N_TOK 8192
#define DIM   384
#define NEXP  8
#define HID   1536
#define OUTD  384
#define CAP_MT 72        // 32-row gather tiles per expert (2304 tokens, mean 2048 + 6 sigma)
#define CAP_TOK 2304
#define CAP_TB 18        // 128-row expert blocks per expert
#define HPITCH 136       // h_lds row pitch in shorts (272B): 16B-aligned, measured 0 conflicts

typedef __attribute__((ext_vector_type(8)))  __bf16 bf16x8;
typedef __attribute__((ext_vector_type(16))) float  f32x16;

__device__ __forceinline__ unsigned short f2bf(float f) {
    unsigned u = __float_as_uint(f);
    u += 0x7FFF + ((u >> 16) & 1);          // round-to-nearest-even
    return (unsigned short)(u >> 16);
}

__device__ __forceinline__ float gelu_exact(float x) {
    return 0.5f * x * (1.0f + erff(x * 0.70710678118654752f));
}

// async global->LDS, 16B per lane; LDS dest = wave-uniform tile base (HW adds lane*16)
__device__ __forceinline__ void cp16(const unsigned short* g, unsigned short* l) {
    __builtin_amdgcn_global_load_lds(
        (const __attribute__((address_space(1))) unsigned int*)g,
        (__attribute__((address_space(3))) unsigned int*)l, 16, 0, 0);
}

// ---------------------------------------------------------------- init (cnt only; yp4 needs no zeroing)
__global__ void init_kernel(int* __restrict__ cnt) {
    if (threadIdx.x < NEXP) cnt[threadIdx.x] = 0;
}

// ------------------------------------------------- W[e][K][N] fp32 -> B-fragment order bf16
// dst[((e*NT + nt)*KT + kt)*64 + l][j] = bf16(src[e][kt*16 + (l>>5)*8 + j][nt*32 + (l&31)])
__global__ void swizzle_kernel(const float* __restrict__ src, unsigned short* __restrict__ dst,
                               int K, int N, int NT, int KT) {
    int gid = blockIdx.x * blockDim.x + threadIdx.x;
    int total = NEXP * NT * KT * 64;
    if (gid >= total) return;
    int l  = gid & 63;
    int kt = (gid >> 6) % KT;
    int nt = ((gid >> 6) / KT) % NT;
    int e  = gid / (64 * KT * NT);
    const float* s = src + ((size_t)e * K + kt * 16 + (l >> 5) * 8) * N + nt * 32 + (l & 31);
    unsigned short r[8];
    #pragma unroll
    for (int j = 0; j < 8; ++j) r[j] = f2bf(s[(size_t)j * N]);
    *(uint4*)(dst + (size_t)gid * 8) = *(uint4*)r;
}

// ---------------------------------------------------------------- router
__global__ void router_kernel(const float* __restrict__ x, const float* __restrict__ Wg,
                              const float* __restrict__ bg, int* __restrict__ cnt,
                              int* __restrict__ btok, int* __restrict__ tokmap,
                              float* __restrict__ gmap) {
    __shared__ float WgL[DIM * NEXP];
    __shared__ int lcnt[NEXP];
    __shared__ int lbase[NEXP];
    int tid = threadIdx.x;
    for (int i = tid; i < DIM * NEXP; i += 256) WgL[i] = Wg[i];
    if (tid < NEXP) lcnt[tid] = 0;
    __syncthreads();

    int t = blockIdx.x * 256 + tid;
    float lg[NEXP];
    #pragma unroll
    for (int e = 0; e < NEXP; ++e) lg[e] = bg[e];

    const float4* xr = (const float4*)(x + (size_t)t * DIM);
    for (int d4 = 0; d4 < DIM / 4; ++d4) {
        float4 v = xr[d4];
        const float* wrow = &WgL[d4 * 4 * NEXP];
        #pragma unroll
        for (int e = 0; e < NEXP; ++e)
            lg[e] += v.x * wrow[e] + v.y * wrow[NEXP + e]
                   + v.z * wrow[2 * NEXP + e] + v.w * wrow[3 * NEXP + e];
    }

    float v0 = -INFINITY, v1 = -INFINITY; int i0 = 0, i1 = 0;
    #pragma unroll
    for (int e = 0; e < NEXP; ++e) {
        float v = lg[e];
        if (v > v0)      { v1 = v0; i1 = i0; v0 = v; i0 = e; }
        else if (v > v1) { v1 = v;  i1 = e; }
    }
    float e1 = expf(v1 - v0);
    float g0 = 1.f / (1.f + e1);
    float g1 = e1  / (1.f + e1);

    int p0 = atomicAdd(&lcnt[i0], 1);
    int p1 = atomicAdd(&lcnt[i1], 1);
    __syncthreads();
    if (tid < NEXP) lbase[tid] = atomicAdd(&cnt[tid], lcnt[tid]);
    __syncthreads();
    int o0 = lbase[i0] + p0, o1 = lbase[i1] + p1;
    btok[i0 * N_TOK + o0] = t;
    btok[i1 * N_TOK + o1] = t;
    ((int4*)tokmap)[t] = make_int4(i0, o0, i1, o1);
    ((float2*)gmap)[t] = make_float2(g0, g1);
}

// ------------------------------------------ gather x rows into A-fragment order (bf16)
__global__ void gather_kernel(const float* __restrict__ x, const int* __restrict__ cnt,
                              const int* __restrict__ btok, unsigned short* __restrict__ xg) {
    int mt = blockIdx.x, e = blockIdx.y;
    int cntE = cnt[e];
    if (mt * 32 >= cntE) return;
    int tid = threadIdx.x;                 // 256
    int m = tid & 31, kt0 = tid >> 5;      // 32 x 8
    int pos = mt * 32 + m;
    int idx = (pos < cntE) ? pos : cntE - 1;   // clamp pad rows (masked later)
    int tok = btok[e * N_TOK + idx];
    const float* xr = x + (size_t)tok * DIM;
    #pragma unroll
    for (int kk = 0; kk < 3; ++kk) {
        int kt = kt0 + kk * 8;
        #pragma unroll
        for (int kh = 0; kh < 2; ++kh) {
            float4 v0 = *(const float4*)(xr + kt * 16 + kh * 8);
            float4 v1 = *(const float4*)(xr + kt * 16 + kh * 8 + 4);
            unsigned short rr[8];
            rr[0] = f2bf(v0.x); rr[1] = f2bf(v0.y); rr[2] = f2bf(v0.z); rr[3] = f2bf(v0.w);
            rr[4] = f2bf(v1.x); rr[5] = f2bf(v1.y); rr[6] = f2bf(v1.z); rr[7] = f2bf(v1.w);
            *(uint4*)(xg + (size_t)(((e * CAP_MT + mt) * 24 + kt) * 64 + kh * 32 + m) * 8) =
                *(uint4*)rr;
        }
    }
}

// ---------------------------------------------------------------- fused expert MLP
// 512 thr (8 waves). Block = (e = L&7 [XCD-pin], hs quarter of HID, tb: 128 tokens).
// All fragments staged via async global_load_lds into 32KB LDS (tiles are 1KB, frag order),
// consumed with conflict-free ds_read_b128. m97 2-barrier structure.
// Partials written with PLAIN stores to private slice yp4[hs][e][pos][384] — zero atomics.
__global__ __launch_bounds__(512, 2) void expert_kernel(
        const unsigned short* __restrict__ xg,  const unsigned short* __restrict__ w1s,
        const unsigned short* __restrict__ w2s, const float* __restrict__ b1,
        const int* __restrict__ cnt,            float* __restrict__ yp4) {
    int L  = blockIdx.x;
    int e  = L & 7;
    int r  = L >> 3;
    int hs = r & 3;               // hid-slice (384 cols)
    int tb = r >> 2;              // 128-token block
    int cntE = cnt[e];
    if (tb * 128 >= cntE) return;

    __shared__ unsigned short stg[16384];            // 32 KB stage buffer (32 x 1KB tiles)
    __shared__ unsigned short h_lds[128 * HPITCH];   // 34.8 KB

    int tid  = threadIdx.x;
    int wave = tid >> 6, lane = tid & 63;
    int m31 = lane & 31, kh = lane >> 5;
    int mh = wave >> 2, ni = wave & 3;    // GEMM1: mh = row-half (64 rows), ni = 32-col tile
    int oj = ni;                          // GEMM2: oj = 96-col out group, same mh

    f32x16 acc2[6];
    #pragma unroll
    for (int i = 0; i < 6; ++i)
        acc2[i] = (f32x16){0.f,0.f,0.f,0.f,0.f,0.f,0.f,0.f,0.f,0.f,0.f,0.f,0.f,0.f,0.f,0.f};

    const unsigned short* xg_e = xg + ((size_t)(e * CAP_MT + tb * 4) * 24) * 512;
    const unsigned short* w1_e = w1s + ((size_t)(e * 48 + hs * 12) * 24) * 512;

    for (int hc = 0; hc < 3; ++hc) {
        // ================= GEMM1: h[128][128] = x[128][384] @ W1 chunk =================
        f32x16 acc1[2];
        acc1[0] = (f32x16){0.f,0.f,0.f,0.f,0.f,0.f,0.f,0.f,0.f,0.f,0.f,0.f,0.f,0.f,0.f,0.f};
        acc1[1] = acc1[0];
        for (int ktg = 0; ktg < 6; ++ktg) {          // 4 kt (=64 K) per group
            __syncthreads();                          // stg free (prev consume done)
            #pragma unroll
            for (int i = 0; i < 4; ++i) {             // 32 tiles: 16 x-tiles + 16 W1-tiles
                int tl = i * 8 + wave;
                const unsigned short* src;
                if (tl < 16) {                        // x tile: [mt 0..3][kt 0..3]
                    int mt = tl >> 2, kt = tl & 3;
                    src = xg_e + ((size_t)mt * 24 + ktg * 4 + kt) * 512;
                } else {                              // W1 tile: [ni 0..3][kt 0..3]
                    int t2 = tl - 16;
                    int nn = t2 >> 2, kt = t2 & 3;
                    src = w1_e + ((size_t)(hc * 4 + nn) * 24 + ktg * 4 + kt) * 512;
                }
                cp16(src + lane * 8, &stg[tl * 512]);
            }
            __syncthreads();                          // drain vmcnt: staged data visible
            #pragma unroll
            for (int kt = 0; kt < 4; ++kt) {
                bf16x8 b  = *(const bf16x8*)&stg[(16 + ni * 4 + kt) * 512 + lane * 8];
                bf16x8 a0 = *(const bf16x8*)&stg[((mh * 2 + 0) * 4 + kt) * 512 + lane * 8];
                bf16x8 a1 = *(const bf16x8*)&stg[((mh * 2 + 1) * 4 + kt) * 512 + lane * 8];
                acc1[0] = __builtin_amdgcn_mfma_f32_32x32x16_bf16(a0, b, acc1[0], 0, 0, 0);
                acc1[1] = __builtin_amdgcn_mfma_f32_32x32x16_bf16(a1, b, acc1[1], 0, 0, 0);
            }
        }
        // ---- bias + exact gelu -> h_lds (C-layout rows, pitch 136)
        int colL = ni * 32 + m31;
        float b1v = b1[e * HID + hs * 384 + hc * 128 + colL];
        #pragma unroll
        for (int s = 0; s < 2; ++s)
            #pragma unroll
            for (int rr = 0; rr < 16; ++rr) {
                int row = mh * 64 + s * 32 + (rr & 3) + 8 * (rr >> 2) + 4 * kh;
                h_lds[row * HPITCH + colL] = f2bf(gelu_exact(acc1[s][rr] + b1v));
            }
        // ================= GEMM2: y[128][384] += h[128][128] @ W2 chunk ================
        for (int ksg = 0; ksg < 4; ++ksg) {          // 2 ks (=32 K) per group
            __syncthreads();                          // h visible (ksg=0) + stg free
            #pragma unroll
            for (int i = 0; i < 3; ++i) {             // 24 W2 tiles: [nc 0..11][j 0..1]
                int tl = i * 8 + wave;
                int nc = tl >> 1, j = tl & 1;
                const unsigned short* src =
                    w2s + ((size_t)(e * 12 + nc) * 96 + hs * 24 + hc * 8 + ksg * 2 + j) * 512;
                cp16(src + lane * 8, &stg[tl * 512]);
            }
            __syncthreads();
            #pragma unroll
            for (int j = 0; j < 2; ++j) {
                int kcol = (ksg * 2 + j) * 16 + kh * 8;
                bf16x8 a0 = *(const bf16x8*)&h_lds[(mh * 64 +  0 + m31) * HPITCH + kcol];
                bf16x8 a1 = *(const bf16x8*)&h_lds[(mh * 64 + 32 + m31) * HPITCH + kcol];
                #pragma unroll
                for (int o = 0; o < 3; ++o) {
                    bf16x8 b = *(const bf16x8*)&stg[((oj * 3 + o) * 2 + j) * 512 + lane * 8];
                    acc2[o * 2 + 0] = __builtin_amdgcn_mfma_f32_32x32x16_bf16(a0, b, acc2[o * 2 + 0], 0, 0, 0);
                    acc2[o * 2 + 1] = __builtin_amdgcn_mfma_f32_32x32x16_bf16(a1, b, acc2[o * 2 + 1], 0, 0, 0);
                }
            }
        }
    }

    // ---- epilogue: PLAIN stores to private partial slice (128B coalesced per half-wave)
    float* ypb = yp4 + ((size_t)(hs * NEXP + e) * CAP_TOK) * OUTD;
    #pragma unroll
    for (int o = 0; o < 3; ++o) {
        int col = (oj * 3 + o) * 32 + m31;
        #pragma unroll
        for (int s = 0; s < 2; ++s)
            #pragma unroll
            for (int rr = 0; rr < 16; ++rr) {
                int row = mh * 64 + s * 32 + (rr & 3) + 8 * (rr >> 2) + 4 * kh;
                int pos = tb * 128 + row;
                if (pos < cntE)
                    ypb[(size_t)pos * OUTD + col] = acc2[o * 2 + s][rr];
            }
    }
}

// ------------------------------- reduce: out = sum_k g_k * (sum_hs yp4[hs][e_k][pos_k] + b2[e_k])
__global__ void reduce_kernel(const float* __restrict__ yp4, const int* __restrict__ tokmap,
                              const float* __restrict__ gmap, const float* __restrict__ b2,
                              float* __restrict__ out) {
    int gid = blockIdx.x * 256 + threadIdx.x;      // N_TOK * 96 threads
    int t = gid / 96, q = gid - t * 96;
    int4   tm = ((const int4*)tokmap)[t];
    float2 g  = ((const float2*)gmap)[t];
    const size_t hstep = (size_t)NEXP * CAP_TOK * OUTD;
    const float* p0 = yp4 + ((size_t)tm.x * CAP_TOK + tm.y) * OUTD + q * 4;
    const float* p1 = yp4 + ((size_t)tm.z * CAP_TOK + tm.w) * OUTD + q * 4;
    float4 y0 = make_float4(0.f, 0.f, 0.f, 0.f);
    float4 y1 = make_float4(0.f, 0.f, 0.f, 0.f);
    #pragma unroll
    for (int h = 0; h < 4; ++h) {
        float4 a = *(const float4*)(p0 + h * hstep);
        float4 b = *(const float4*)(p1 + h * hstep);
        y0.x += a.x; y0.y += a.y; y0.z += a.z; y0.w += a.w;
        y1.x += b.x; y1.y += b.y; y1.z += b.z; y1.w += b.w;
    }
    float4 c0 = *(const float4*)&b2[tm.x * OUTD + q * 4];
    float4 c1 = *(const float4*)&b2[tm.z * OUTD + q * 4];
    float4 rv;
    rv.x = g.x * (y0.x + c0.x) + g.y * (y1.x + c1.x);
    rv.y = g.x * (y0.y + c0.y) + g.y * (y1.y + c1.y);
    rv.z = g.x * (y0.z + c0.z) + g.y * (y1.z + c1.z);
    rv.w = g.x * (y0.w + c0.w) + g.y * (y1.w + c1.w);
    *(float4*)&out[(size_t)t * OUTD + q * 4] = rv;
}

// ---------------------------------------------------------------- launch
extern "C" void kernel_launch(void* const* d_in, const int* in_sizes, int n_in,
                              void* d_out, int out_size, void* d_ws, size_t ws_size,
                              hipStream_t stream) {
    const float* x  = (const float*)d_in[0];
    const float* Wg = (const float*)d_in[1];
    const float* bg = (const float*)d_in[2];
    const float* W1 = (const float*)d_in[3];
    const float* b1 = (const float*)d_in[4];
    const float* W2 = (const float*)d_in[5];
    const float* b2 = (const float*)d_in[6];
    float* out = (float*)d_out;

    char* ws = (char*)d_ws;                                    // all offsets 1KB-aligned
    int*            cnt    = (int*)ws;                         // 32 B
    int*            btok   = (int*)(ws + 1024);                // 256 KB
    int*            tokmap = (int*)(ws + 263168);              // 128 KB
    float*          gmap   = (float*)(ws + 394240);            // 64 KB
    unsigned short* xg     = (unsigned short*)(ws + 459776);   // 13.5 MB
    unsigned short* w1s    = (unsigned short*)(ws + 14615552); // 9.44 MB
    unsigned short* w2s    = (unsigned short*)(ws + 24052736); // 9.44 MB
    float*          yp4    = (float*)(ws + 33489920);          // 113.2 MB -> end ~140 MB

    hipLaunchKernelGGL(init_kernel, dim3(1), dim3(64), 0, stream, cnt);
    // W1: K=DIM, N=HID -> NT=48, KT=24 ; W2: K=HID, N=OUTD -> NT=12, KT=96
    hipLaunchKernelGGL(swizzle_kernel, dim3(NEXP * 48 * 24 * 64 / 256), dim3(256), 0, stream,
                       W1, w1s, DIM, HID, 48, 24);
    hipLaunchKernelGGL(swizzle_kernel, dim3(NEXP * 12 * 96 * 64 / 256), dim3(256), 0, stream,
                       W2, w2s, HID, OUTD, 12, 96);
    hipLaunchKernelGGL(router_kernel, dim3(N_TOK / 256), dim3(256), 0, stream,
                       x, Wg, bg, cnt, btok, tokmap, gmap);
    hipLaunchKernelGGL(gather_kernel, dim3(CAP_MT, NEXP), dim3(256), 0, stream,
                       x, cnt, btok, xg);
    hipLaunchKernelGGL(expert_kernel, dim3(NEXP * 4 * CAP_TB), dim3(512), 0, stream,
                       xg, w1s, w2s, b1, cnt, yp4);
    hipLaunchKernelGGL(reduce_kernel, dim3(N_TOK * 96 / 256), dim3(256), 0, stream,
                       yp4, tokmap, gmap, b2, out);
}

// Round 7
// 259.743 us; speedup vs baseline: 1.3342x; 1.0289x over previous
//
#include <hip/hip_runtime.h>
#include <cmath>

#define N_TOK 8192
#define DIM   384
#define NEXP  8
#define HID   1536
#define OUTD  384
#define CAP_MT 72        // 32-row gather tiles per expert (2304 tokens, mean 2048 + 6 sigma)
#define CAP_TOK 2304
#define CAP_TB 18        // 128-row expert blocks per expert
#define HPITCH 136       // h_lds row pitch in shorts (272B): 16B-aligned, measured 0 conflicts

typedef __attribute__((ext_vector_type(8)))  __bf16 bf16x8;
typedef __attribute__((ext_vector_type(16))) float  f32x16;
typedef __attribute__((ext_vector_type(4)))  float  f32x4;   // for nontemporal builtins

__device__ __forceinline__ unsigned short f2bf(float f) {
    unsigned u = __float_as_uint(f);
    u += 0x7FFF + ((u >> 16) & 1);          // round-to-nearest-even
    return (unsigned short)(u >> 16);
}

__device__ __forceinline__ float gelu_exact(float x) {
    return 0.5f * x * (1.0f + erff(x * 0.70710678118654752f));
}

// async global->LDS, 16B per lane; LDS dest = wave-uniform tile base (HW adds lane*16)
__device__ __forceinline__ void cp16(const unsigned short* g, unsigned short* l) {
    __builtin_amdgcn_global_load_lds(
        (const __attribute__((address_space(1))) unsigned int*)g,
        (__attribute__((address_space(3))) unsigned int*)l, 16, 0, 0);
}

// ---------------------------------------------------------------- init (cnt only)
__global__ void init_kernel(int* __restrict__ cnt) {
    if (threadIdx.x < NEXP) cnt[threadIdx.x] = 0;
}

// ------------------------------------------------- W[e][K][N] fp32 -> B-fragment order bf16
// dst[((e*NT + nt)*KT + kt)*64 + l][j] = bf16(src[e][kt*16 + (l>>5)*8 + j][nt*32 + (l&31)])
__global__ void swizzle_kernel(const float* __restrict__ src, unsigned short* __restrict__ dst,
                               int K, int N, int NT, int KT) {
    int gid = blockIdx.x * blockDim.x + threadIdx.x;
    int total = NEXP * NT * KT * 64;
    if (gid >= total) return;
    int l  = gid & 63;
    int kt = (gid >> 6) % KT;
    int nt = ((gid >> 6) / KT) % NT;
    int e  = gid / (64 * KT * NT);
    const float* s = src + ((size_t)e * K + kt * 16 + (l >> 5) * 8) * N + nt * 32 + (l & 31);
    unsigned short r[8];
    #pragma unroll
    for (int j = 0; j < 8; ++j) r[j] = f2bf(s[(size_t)j * N]);
    *(uint4*)(dst + (size_t)gid * 8) = *(uint4*)r;
}

// ---------------------------------------------------------------- router
__global__ void router_kernel(const float* __restrict__ x, const float* __restrict__ Wg,
                              const float* __restrict__ bg, int* __restrict__ cnt,
                              int* __restrict__ btok, int* __restrict__ tokmap,
                              float* __restrict__ gmap) {
    __shared__ float WgL[DIM * NEXP];
    __shared__ int lcnt[NEXP];
    __shared__ int lbase[NEXP];
    int tid = threadIdx.x;
    for (int i = tid; i < DIM * NEXP; i += 256) WgL[i] = Wg[i];
    if (tid < NEXP) lcnt[tid] = 0;
    __syncthreads();

    int t = blockIdx.x * 256 + tid;
    float lg[NEXP];
    #pragma unroll
    for (int e = 0; e < NEXP; ++e) lg[e] = bg[e];

    const float4* xr = (const float4*)(x + (size_t)t * DIM);
    for (int d4 = 0; d4 < DIM / 4; ++d4) {
        float4 v = xr[d4];
        const float* wrow = &WgL[d4 * 4 * NEXP];
        #pragma unroll
        for (int e = 0; e < NEXP; ++e)
            lg[e] += v.x * wrow[e] + v.y * wrow[NEXP + e]
                   + v.z * wrow[2 * NEXP + e] + v.w * wrow[3 * NEXP + e];
    }

    float v0 = -INFINITY, v1 = -INFINITY; int i0 = 0, i1 = 0;
    #pragma unroll
    for (int e = 0; e < NEXP; ++e) {
        float v = lg[e];
        if (v > v0)      { v1 = v0; i1 = i0; v0 = v; i0 = e; }
        else if (v > v1) { v1 = v;  i1 = e; }
    }
    float e1 = expf(v1 - v0);
    float g0 = 1.f / (1.f + e1);
    float g1 = e1  / (1.f + e1);

    int p0 = atomicAdd(&lcnt[i0], 1);
    int p1 = atomicAdd(&lcnt[i1], 1);
    __syncthreads();
    if (tid < NEXP) lbase[tid] = atomicAdd(&cnt[tid], lcnt[tid]);
    __syncthreads();
    int o0 = lbase[i0] + p0, o1 = lbase[i1] + p1;
    btok[i0 * N_TOK + o0] = t;
    btok[i1 * N_TOK + o1] = t;
    ((int4*)tokmap)[t] = make_int4(i0, o0, i1, o1);
    ((float2*)gmap)[t] = make_float2(g0, g1);
}

// ------------------------------------------ gather x rows into A-fragment order (bf16)
__global__ void gather_kernel(const float* __restrict__ x, const int* __restrict__ cnt,
                              const int* __restrict__ btok, unsigned short* __restrict__ xg) {
    int mt = blockIdx.x, e = blockIdx.y;
    int cntE = cnt[e];
    if (mt * 32 >= cntE) return;
    int tid = threadIdx.x;                 // 256
    int m = tid & 31, kt0 = tid >> 5;      // 32 x 8
    int pos = mt * 32 + m;
    int idx = (pos < cntE) ? pos : cntE - 1;   // clamp pad rows (masked later)
    int tok = btok[e * N_TOK + idx];
    const float* xr = x + (size_t)tok * DIM;
    #pragma unroll
    for (int kk = 0; kk < 3; ++kk) {
        int kt = kt0 + kk * 8;
        #pragma unroll
        for (int kh = 0; kh < 2; ++kh) {
            float4 v0 = *(const float4*)(xr + kt * 16 + kh * 8);
            float4 v1 = *(const float4*)(xr + kt * 16 + kh * 8 + 4);
            unsigned short rr[8];
            rr[0] = f2bf(v0.x); rr[1] = f2bf(v0.y); rr[2] = f2bf(v0.z); rr[3] = f2bf(v0.w);
            rr[4] = f2bf(v1.x); rr[5] = f2bf(v1.y); rr[6] = f2bf(v1.z); rr[7] = f2bf(v1.w);
            *(uint4*)(xg + (size_t)(((e * CAP_MT + mt) * 24 + kt) * 64 + kh * 32 + m) * 8) =
                *(uint4*)rr;
        }
    }
}

// ---------------------------------------------------------------- fused expert MLP
// 512 thr (8 waves). Block = (e = L&7 [XCD-pin], hs quarter of HID, tb: 128 tokens).
// All fragments staged via async global_load_lds into 32KB LDS, consumed with
// conflict-free ds_read_b128. Partials go out via NON-TEMPORAL stores so the
// 98MB yp4 stream does not thrash the per-XCD L2 that caches W/x tiles.
__global__ __launch_bounds__(512, 2) void expert_kernel(
        const unsigned short* __restrict__ xg,  const unsigned short* __restrict__ w1s,
        const unsigned short* __restrict__ w2s, const float* __restrict__ b1,
        const int* __restrict__ cnt,            float* __restrict__ yp4) {
    int L  = blockIdx.x;
    int e  = L & 7;
    int r  = L >> 3;
    int hs = r & 3;               // hid-slice (384 cols)
    int tb = r >> 2;              // 128-token block
    int cntE = cnt[e];
    if (tb * 128 >= cntE) return;

    __shared__ unsigned short stg[16384];            // 32 KB stage buffer (32 x 1KB tiles)
    __shared__ unsigned short h_lds[128 * HPITCH];   // 34.8 KB

    int tid  = threadIdx.x;
    int wave = tid >> 6, lane = tid & 63;
    int m31 = lane & 31, kh = lane >> 5;
    int mh = wave >> 2, ni = wave & 3;    // GEMM1: mh = row-half (64 rows), ni = 32-col tile
    int oj = ni;                          // GEMM2: oj = 96-col out group, same mh

    f32x16 acc2[6];
    #pragma unroll
    for (int i = 0; i < 6; ++i)
        acc2[i] = (f32x16){0.f,0.f,0.f,0.f,0.f,0.f,0.f,0.f,0.f,0.f,0.f,0.f,0.f,0.f,0.f,0.f};

    const unsigned short* xg_e = xg + ((size_t)(e * CAP_MT + tb * 4) * 24) * 512;
    const unsigned short* w1_e = w1s + ((size_t)(e * 48 + hs * 12) * 24) * 512;

    for (int hc = 0; hc < 3; ++hc) {
        // ================= GEMM1: h[128][128] = x[128][384] @ W1 chunk =================
        f32x16 acc1[2];
        acc1[0] = (f32x16){0.f,0.f,0.f,0.f,0.f,0.f,0.f,0.f,0.f,0.f,0.f,0.f,0.f,0.f,0.f,0.f};
        acc1[1] = acc1[0];
        for (int ktg = 0; ktg < 6; ++ktg) {          // 4 kt (=64 K) per group
            __syncthreads();                          // stg free (prev consume done)
            #pragma unroll
            for (int i = 0; i < 4; ++i) {             // 32 tiles: 16 x-tiles + 16 W1-tiles
                int tl = i * 8 + wave;
                const unsigned short* src;
                if (tl < 16) {                        // x tile: [mt 0..3][kt 0..3]
                    int mt = tl >> 2, kt = tl & 3;
                    src = xg_e + ((size_t)mt * 24 + ktg * 4 + kt) * 512;
                } else {                              // W1 tile: [ni 0..3][kt 0..3]
                    int t2 = tl - 16;
                    int nn = t2 >> 2, kt = t2 & 3;
                    src = w1_e + ((size_t)(hc * 4 + nn) * 24 + ktg * 4 + kt) * 512;
                }
                cp16(src + lane * 8, &stg[tl * 512]);
            }
            __syncthreads();                          // drain vmcnt: staged data visible
            #pragma unroll
            for (int kt = 0; kt < 4; ++kt) {
                bf16x8 b  = *(const bf16x8*)&stg[(16 + ni * 4 + kt) * 512 + lane * 8];
                bf16x8 a0 = *(const bf16x8*)&stg[((mh * 2 + 0) * 4 + kt) * 512 + lane * 8];
                bf16x8 a1 = *(const bf16x8*)&stg[((mh * 2 + 1) * 4 + kt) * 512 + lane * 8];
                acc1[0] = __builtin_amdgcn_mfma_f32_32x32x16_bf16(a0, b, acc1[0], 0, 0, 0);
                acc1[1] = __builtin_amdgcn_mfma_f32_32x32x16_bf16(a1, b, acc1[1], 0, 0, 0);
            }
        }
        // ---- bias + exact gelu -> h_lds (C-layout rows, pitch 136)
        int colL = ni * 32 + m31;
        float b1v = b1[e * HID + hs * 384 + hc * 128 + colL];
        #pragma unroll
        for (int s = 0; s < 2; ++s)
            #pragma unroll
            for (int rr = 0; rr < 16; ++rr) {
                int row = mh * 64 + s * 32 + (rr & 3) + 8 * (rr >> 2) + 4 * kh;
                h_lds[row * HPITCH + colL] = f2bf(gelu_exact(acc1[s][rr] + b1v));
            }
        // ================= GEMM2: y[128][384] += h[128][128] @ W2 chunk ================
        for (int ksg = 0; ksg < 4; ++ksg) {          // 2 ks (=32 K) per group
            __syncthreads();                          // h visible (ksg=0) + stg free
            #pragma unroll
            for (int i = 0; i < 3; ++i) {             // 24 W2 tiles: [nc 0..11][j 0..1]
                int tl = i * 8 + wave;
                int nc = tl >> 1, j = tl & 1;
                const unsigned short* src =
                    w2s + ((size_t)(e * 12 + nc) * 96 + hs * 24 + hc * 8 + ksg * 2 + j) * 512;
                cp16(src + lane * 8, &stg[tl * 512]);
            }
            __syncthreads();
            #pragma unroll
            for (int j = 0; j < 2; ++j) {
                int kcol = (ksg * 2 + j) * 16 + kh * 8;
                bf16x8 a0 = *(const bf16x8*)&h_lds[(mh * 64 +  0 + m31) * HPITCH + kcol];
                bf16x8 a1 = *(const bf16x8*)&h_lds[(mh * 64 + 32 + m31) * HPITCH + kcol];
                #pragma unroll
                for (int o = 0; o < 3; ++o) {
                    bf16x8 b = *(const bf16x8*)&stg[((oj * 3 + o) * 2 + j) * 512 + lane * 8];
                    acc2[o * 2 + 0] = __builtin_amdgcn_mfma_f32_32x32x16_bf16(a0, b, acc2[o * 2 + 0], 0, 0, 0);
                    acc2[o * 2 + 1] = __builtin_amdgcn_mfma_f32_32x32x16_bf16(a1, b, acc2[o * 2 + 1], 0, 0, 0);
                }
            }
        }
    }

    // ---- epilogue: NON-TEMPORAL stores to private partial slice (no L2 pollution)
    float* ypb = yp4 + ((size_t)(hs * NEXP + e) * CAP_TOK) * OUTD;
    #pragma unroll
    for (int o = 0; o < 3; ++o) {
        int col = (oj * 3 + o) * 32 + m31;
        #pragma unroll
        for (int s = 0; s < 2; ++s)
            #pragma unroll
            for (int rr = 0; rr < 16; ++rr) {
                int row = mh * 64 + s * 32 + (rr & 3) + 8 * (rr >> 2) + 4 * kh;
                int pos = tb * 128 + row;
                if (pos < cntE)
                    __builtin_nontemporal_store(acc2[o * 2 + s][rr],
                                                &ypb[(size_t)pos * OUTD + col]);
            }
    }
}

// ------------------------------- reduce: out = sum_k g_k * (sum_hs yp4[hs][e_k][pos_k] + b2[e_k])
__global__ void reduce_kernel(const float* __restrict__ yp4, const int* __restrict__ tokmap,
                              const float* __restrict__ gmap, const float* __restrict__ b2,
                              float* __restrict__ out) {
    int gid = blockIdx.x * 256 + threadIdx.x;      // N_TOK * 96 threads
    int t = gid / 96, q = gid - t * 96;
    int4   tm = ((const int4*)tokmap)[t];
    float2 g  = ((const float2*)gmap)[t];
    const size_t hstep = (size_t)NEXP * CAP_TOK * OUTD;
    const float* p0 = yp4 + ((size_t)tm.x * CAP_TOK + tm.y) * OUTD + q * 4;
    const float* p1 = yp4 + ((size_t)tm.z * CAP_TOK + tm.w) * OUTD + q * 4;
    f32x4 y0 = (f32x4){0.f, 0.f, 0.f, 0.f};
    f32x4 y1 = (f32x4){0.f, 0.f, 0.f, 0.f};
    #pragma unroll
    for (int h = 0; h < 4; ++h) {
        y0 += __builtin_nontemporal_load((const f32x4*)(p0 + h * hstep));
        y1 += __builtin_nontemporal_load((const f32x4*)(p1 + h * hstep));
    }
    f32x4 c0 = *(const f32x4*)&b2[tm.x * OUTD + q * 4];
    f32x4 c1 = *(const f32x4*)&b2[tm.z * OUTD + q * 4];
    f32x4 rv = g.x * (y0 + c0) + g.y * (y1 + c1);
    __builtin_nontemporal_store(rv, (f32x4*)&out[(size_t)t * OUTD + q * 4]);
}

// ---------------------------------------------------------------- launch
extern "C" void kernel_launch(void* const* d_in, const int* in_sizes, int n_in,
                              void* d_out, int out_size, void* d_ws, size_t ws_size,
                              hipStream_t stream) {
    const float* x  = (const float*)d_in[0];
    const float* Wg = (const float*)d_in[1];
    const float* bg = (const float*)d_in[2];
    const float* W1 = (const float*)d_in[3];
    const float* b1 = (const float*)d_in[4];
    const float* W2 = (const float*)d_in[5];
    const float* b2 = (const float*)d_in[6];
    float* out = (float*)d_out;

    char* ws = (char*)d_ws;                                    // all offsets 1KB-aligned
    int*            cnt    = (int*)ws;                         // 32 B
    int*            btok   = (int*)(ws + 1024);                // 256 KB
    int*            tokmap = (int*)(ws + 263168);              // 128 KB
    float*          gmap   = (float*)(ws + 394240);            // 64 KB
    unsigned short* xg     = (unsigned short*)(ws + 459776);   // 13.5 MB
    unsigned short* w1s    = (unsigned short*)(ws + 14615552); // 9.44 MB
    unsigned short* w2s    = (unsigned short*)(ws + 24052736); // 9.44 MB
    float*          yp4    = (float*)(ws + 33489920);          // 113.2 MB -> end ~140 MB

    hipLaunchKernelGGL(init_kernel, dim3(1), dim3(64), 0, stream, cnt);
    // W1: K=DIM, N=HID -> NT=48, KT=24 ; W2: K=HID, N=OUTD -> NT=12, KT=96
    hipLaunchKernelGGL(swizzle_kernel, dim3(NEXP * 48 * 24 * 64 / 256), dim3(256), 0, stream,
                       W1, w1s, DIM, HID, 48, 24);
    hipLaunchKernelGGL(swizzle_kernel, dim3(NEXP * 12 * 96 * 64 / 256), dim3(256), 0, stream,
                       W2, w2s, HID, OUTD, 12, 96);
    hipLaunchKernelGGL(router_kernel, dim3(N_TOK / 256), dim3(256), 0, stream,
                       x, Wg, bg, cnt, btok, tokmap, gmap);
    hipLaunchKernelGGL(gather_kernel, dim3(CAP_MT, NEXP), dim3(256), 0, stream,
                       x, cnt, btok, xg);
    hipLaunchKernelGGL(expert_kernel, dim3(NEXP * 4 * CAP_TB), dim3(512), 0, stream,
                       xg, w1s, w2s, b1, cnt, yp4);
    hipLaunchKernelGGL(reduce_kernel, dim3(N_TOK * 96 / 256), dim3(256), 0, stream,
                       yp4, tokmap, gmap, b2, out);
}

// Round 8
// 247.029 us; speedup vs baseline: 1.4029x; 1.0515x over previous
//
#include <hip/hip_runtime.h>
#include <cmath>

#define N_TOK 8192
#define DIM   384
#define NEXP  8
#define HID   1536
#define OUTD  384
#define CAP_MT 72        // 32-row gather tiles per expert (2304 tokens, mean 2048 + 6 sigma)
#define CAP_TOK 2304
#define CAP_TB 18        // 128-row expert blocks per expert
#define HPITCH 136       // h_lds row pitch in shorts (272B): 16B-aligned, measured 0 conflicts

typedef __attribute__((ext_vector_type(8)))  __bf16 bf16x8;
typedef __attribute__((ext_vector_type(16))) float  f32x16;
typedef __attribute__((ext_vector_type(4)))  float  f32x4;          // nontemporal builtins
typedef __attribute__((ext_vector_type(8)))  unsigned short u16x8;  // nontemporal bf16 loads

__device__ __forceinline__ unsigned short f2bf(float f) {
    unsigned u = __float_as_uint(f);
    u += 0x7FFF + ((u >> 16) & 1);          // round-to-nearest-even
    return (unsigned short)(u >> 16);
}

__device__ __forceinline__ float bf2f(unsigned short s) {
    return __uint_as_float(((unsigned)s) << 16);
}

__device__ __forceinline__ float gelu_exact(float x) {
    return 0.5f * x * (1.0f + erff(x * 0.70710678118654752f));
}

// async global->LDS, 16B per lane; LDS dest = wave-uniform tile base (HW adds lane*16)
__device__ __forceinline__ void cp16(const unsigned short* g, unsigned short* l) {
    __builtin_amdgcn_global_load_lds(
        (const __attribute__((address_space(1))) unsigned int*)g,
        (__attribute__((address_space(3))) unsigned int*)l, 16, 0, 0);
}

// ------------------------------------------------- W[e][K][N] fp32 -> B-fragment order bf16
// dst[((e*NT + nt)*KT + kt)*64 + l][j] = bf16(src[e][kt*16 + (l>>5)*8 + j][nt*32 + (l&31)])
// Also zeroes cnt from block 0 when cnt != nullptr (saves a launch).
__global__ void swizzle_kernel(const float* __restrict__ src, unsigned short* __restrict__ dst,
                               int K, int N, int NT, int KT, int* __restrict__ cnt) {
    if (cnt && blockIdx.x == 0 && threadIdx.x < NEXP) cnt[threadIdx.x] = 0;
    int gid = blockIdx.x * blockDim.x + threadIdx.x;
    int total = NEXP * NT * KT * 64;
    if (gid >= total) return;
    int l  = gid & 63;
    int kt = (gid >> 6) % KT;
    int nt = ((gid >> 6) / KT) % NT;
    int e  = gid / (64 * KT * NT);
    const float* s = src + ((size_t)e * K + kt * 16 + (l >> 5) * 8) * N + nt * 32 + (l & 31);
    unsigned short r[8];
    #pragma unroll
    for (int j = 0; j < 8; ++j) r[j] = f2bf(s[(size_t)j * N]);
    *(uint4*)(dst + (size_t)gid * 8) = *(uint4*)r;
}

// ---------------------------------------------------------------- router
__global__ void router_kernel(const float* __restrict__ x, const float* __restrict__ Wg,
                              const float* __restrict__ bg, int* __restrict__ cnt,
                              int* __restrict__ btok, int* __restrict__ tokmap,
                              float* __restrict__ gmap) {
    __shared__ float WgL[DIM * NEXP];
    __shared__ int lcnt[NEXP];
    __shared__ int lbase[NEXP];
    int tid = threadIdx.x;
    for (int i = tid; i < DIM * NEXP; i += 256) WgL[i] = Wg[i];
    if (tid < NEXP) lcnt[tid] = 0;
    __syncthreads();

    int t = blockIdx.x * 256 + tid;
    float lg[NEXP];
    #pragma unroll
    for (int e = 0; e < NEXP; ++e) lg[e] = bg[e];

    const float4* xr = (const float4*)(x + (size_t)t * DIM);
    for (int d4 = 0; d4 < DIM / 4; ++d4) {
        float4 v = xr[d4];
        const float* wrow = &WgL[d4 * 4 * NEXP];
        #pragma unroll
        for (int e = 0; e < NEXP; ++e)
            lg[e] += v.x * wrow[e] + v.y * wrow[NEXP + e]
                   + v.z * wrow[2 * NEXP + e] + v.w * wrow[3 * NEXP + e];
    }

    float v0 = -INFINITY, v1 = -INFINITY; int i0 = 0, i1 = 0;
    #pragma unroll
    for (int e = 0; e < NEXP; ++e) {
        float v = lg[e];
        if (v > v0)      { v1 = v0; i1 = i0; v0 = v; i0 = e; }
        else if (v > v1) { v1 = v;  i1 = e; }
    }
    float e1 = expf(v1 - v0);
    float g0 = 1.f / (1.f + e1);
    float g1 = e1  / (1.f + e1);

    int p0 = atomicAdd(&lcnt[i0], 1);
    int p1 = atomicAdd(&lcnt[i1], 1);
    __syncthreads();
    if (tid < NEXP) lbase[tid] = atomicAdd(&cnt[tid], lcnt[tid]);
    __syncthreads();
    int o0 = lbase[i0] + p0, o1 = lbase[i1] + p1;
    btok[i0 * N_TOK + o0] = t;
    btok[i1 * N_TOK + o1] = t;
    ((int4*)tokmap)[t] = make_int4(i0, o0, i1, o1);
    ((float2*)gmap)[t] = make_float2(g0, g1);
}

// ------------------------------------------ gather x rows into A-fragment order (bf16)
__global__ void gather_kernel(const float* __restrict__ x, const int* __restrict__ cnt,
                              const int* __restrict__ btok, unsigned short* __restrict__ xg) {
    int mt = blockIdx.x, e = blockIdx.y;
    int cntE = cnt[e];
    if (mt * 32 >= cntE) return;
    int tid = threadIdx.x;                 // 256
    int m = tid & 31, kt0 = tid >> 5;      // 32 x 8
    int pos = mt * 32 + m;
    int idx = (pos < cntE) ? pos : cntE - 1;   // clamp pad rows (masked later)
    int tok = btok[e * N_TOK + idx];
    const float* xr = x + (size_t)tok * DIM;
    #pragma unroll
    for (int kk = 0; kk < 3; ++kk) {
        int kt = kt0 + kk * 8;
        #pragma unroll
        for (int kh = 0; kh < 2; ++kh) {
            float4 v0 = *(const float4*)(xr + kt * 16 + kh * 8);
            float4 v1 = *(const float4*)(xr + kt * 16 + kh * 8 + 4);
            unsigned short rr[8];
            rr[0] = f2bf(v0.x); rr[1] = f2bf(v0.y); rr[2] = f2bf(v0.z); rr[3] = f2bf(v0.w);
            rr[4] = f2bf(v1.x); rr[5] = f2bf(v1.y); rr[6] = f2bf(v1.z); rr[7] = f2bf(v1.w);
            *(uint4*)(xg + (size_t)(((e * CAP_MT + mt) * 24 + kt) * 64 + kh * 32 + m) * 8) =
                *(uint4*)rr;
        }
    }
}

// ---------------------------------------------------------------- fused expert MLP
// 512 thr (8 waves). Block = (e = L&7 [XCD-pin], hs quarter of HID, tb: 128 tokens).
// All fragments staged via async global_load_lds into 32KB LDS, consumed with
// conflict-free ds_read_b128. Partials stored in BF16 (halves the L2-polluting
// stream vs fp32; plain stores — nt stores regressed in R7).
__global__ __launch_bounds__(512, 2) void expert_kernel(
        const unsigned short* __restrict__ xg,  const unsigned short* __restrict__ w1s,
        const unsigned short* __restrict__ w2s, const float* __restrict__ b1,
        const int* __restrict__ cnt,            unsigned short* __restrict__ yp4) {
    int L  = blockIdx.x;
    int e  = L & 7;
    int r  = L >> 3;
    int hs = r & 3;               // hid-slice (384 cols)
    int tb = r >> 2;              // 128-token block
    int cntE = cnt[e];
    if (tb * 128 >= cntE) return;

    __shared__ unsigned short stg[16384];            // 32 KB stage buffer (32 x 1KB tiles)
    __shared__ unsigned short h_lds[128 * HPITCH];   // 34.8 KB

    int tid  = threadIdx.x;
    int wave = tid >> 6, lane = tid & 63;
    int m31 = lane & 31, kh = lane >> 5;
    int mh = wave >> 2, ni = wave & 3;    // GEMM1: mh = row-half (64 rows), ni = 32-col tile
    int oj = ni;                          // GEMM2: oj = 96-col out group, same mh

    f32x16 acc2[6];
    #pragma unroll
    for (int i = 0; i < 6; ++i)
        acc2[i] = (f32x16){0.f,0.f,0.f,0.f,0.f,0.f,0.f,0.f,0.f,0.f,0.f,0.f,0.f,0.f,0.f,0.f};

    const unsigned short* xg_e = xg + ((size_t)(e * CAP_MT + tb * 4) * 24) * 512;
    const unsigned short* w1_e = w1s + ((size_t)(e * 48 + hs * 12) * 24) * 512;

    for (int hc = 0; hc < 3; ++hc) {
        // ================= GEMM1: h[128][128] = x[128][384] @ W1 chunk =================
        f32x16 acc1[2];
        acc1[0] = (f32x16){0.f,0.f,0.f,0.f,0.f,0.f,0.f,0.f,0.f,0.f,0.f,0.f,0.f,0.f,0.f,0.f};
        acc1[1] = acc1[0];
        for (int ktg = 0; ktg < 6; ++ktg) {          // 4 kt (=64 K) per group
            __syncthreads();                          // stg free (prev consume done)
            #pragma unroll
            for (int i = 0; i < 4; ++i) {             // 32 tiles: 16 x-tiles + 16 W1-tiles
                int tl = i * 8 + wave;
                const unsigned short* src;
                if (tl < 16) {                        // x tile: [mt 0..3][kt 0..3]
                    int mt = tl >> 2, kt = tl & 3;
                    src = xg_e + ((size_t)mt * 24 + ktg * 4 + kt) * 512;
                } else {                              // W1 tile: [ni 0..3][kt 0..3]
                    int t2 = tl - 16;
                    int nn = t2 >> 2, kt = t2 & 3;
                    src = w1_e + ((size_t)(hc * 4 + nn) * 24 + ktg * 4 + kt) * 512;
                }
                cp16(src + lane * 8, &stg[tl * 512]);
            }
            __syncthreads();                          // drain vmcnt: staged data visible
            #pragma unroll
            for (int kt = 0; kt < 4; ++kt) {
                bf16x8 b  = *(const bf16x8*)&stg[(16 + ni * 4 + kt) * 512 + lane * 8];
                bf16x8 a0 = *(const bf16x8*)&stg[((mh * 2 + 0) * 4 + kt) * 512 + lane * 8];
                bf16x8 a1 = *(const bf16x8*)&stg[((mh * 2 + 1) * 4 + kt) * 512 + lane * 8];
                acc1[0] = __builtin_amdgcn_mfma_f32_32x32x16_bf16(a0, b, acc1[0], 0, 0, 0);
                acc1[1] = __builtin_amdgcn_mfma_f32_32x32x16_bf16(a1, b, acc1[1], 0, 0, 0);
            }
        }
        // ---- bias + exact gelu -> h_lds (C-layout rows, pitch 136)
        int colL = ni * 32 + m31;
        float b1v = b1[e * HID + hs * 384 + hc * 128 + colL];
        #pragma unroll
        for (int s = 0; s < 2; ++s)
            #pragma unroll
            for (int rr = 0; rr < 16; ++rr) {
                int row = mh * 64 + s * 32 + (rr & 3) + 8 * (rr >> 2) + 4 * kh;
                h_lds[row * HPITCH + colL] = f2bf(gelu_exact(acc1[s][rr] + b1v));
            }
        // ================= GEMM2: y[128][384] += h[128][128] @ W2 chunk ================
        for (int ksg = 0; ksg < 4; ++ksg) {          // 2 ks (=32 K) per group
            __syncthreads();                          // h visible (ksg=0) + stg free
            #pragma unroll
            for (int i = 0; i < 3; ++i) {             // 24 W2 tiles: [nc 0..11][j 0..1]
                int tl = i * 8 + wave;
                int nc = tl >> 1, j = tl & 1;
                const unsigned short* src =
                    w2s + ((size_t)(e * 12 + nc) * 96 + hs * 24 + hc * 8 + ksg * 2 + j) * 512;
                cp16(src + lane * 8, &stg[tl * 512]);
            }
            __syncthreads();
            #pragma unroll
            for (int j = 0; j < 2; ++j) {
                int kcol = (ksg * 2 + j) * 16 + kh * 8;
                bf16x8 a0 = *(const bf16x8*)&h_lds[(mh * 64 +  0 + m31) * HPITCH + kcol];
                bf16x8 a1 = *(const bf16x8*)&h_lds[(mh * 64 + 32 + m31) * HPITCH + kcol];
                #pragma unroll
                for (int o = 0; o < 3; ++o) {
                    bf16x8 b = *(const bf16x8*)&stg[((oj * 3 + o) * 2 + j) * 512 + lane * 8];
                    acc2[o * 2 + 0] = __builtin_amdgcn_mfma_f32_32x32x16_bf16(a0, b, acc2[o * 2 + 0], 0, 0, 0);
                    acc2[o * 2 + 1] = __builtin_amdgcn_mfma_f32_32x32x16_bf16(a1, b, acc2[o * 2 + 1], 0, 0, 0);
                }
            }
        }
    }

    // ---- epilogue: plain bf16 stores to private partial slice (64B lines, L2-buffered)
    unsigned short* ypb = yp4 + ((size_t)(hs * NEXP + e) * CAP_TOK) * OUTD;
    #pragma unroll
    for (int o = 0; o < 3; ++o) {
        int col = (oj * 3 + o) * 32 + m31;
        #pragma unroll
        for (int s = 0; s < 2; ++s)
            #pragma unroll
            for (int rr = 0; rr < 16; ++rr) {
                int row = mh * 64 + s * 32 + (rr & 3) + 8 * (rr >> 2) + 4 * kh;
                int pos = tb * 128 + row;
                if (pos < cntE)
                    ypb[(size_t)pos * OUTD + col] = f2bf(acc2[o * 2 + s][rr]);
            }
    }
}

// ----------- reduce: out = sum_k g_k * (sum_hs yp4[hs][e_k][pos_k] + b2[e_k]); bf16 partials
__global__ void reduce_kernel(const unsigned short* __restrict__ yp4,
                              const int* __restrict__ tokmap, const float* __restrict__ gmap,
                              const float* __restrict__ b2, float* __restrict__ out) {
    int gid = blockIdx.x * 256 + threadIdx.x;      // N_TOK * 48 threads
    int t = gid / 48, q = gid - t * 48;            // q: 8-col group
    int4   tm = ((const int4*)tokmap)[t];
    float2 g  = ((const float2*)gmap)[t];
    const size_t hstep = (size_t)NEXP * CAP_TOK * OUTD;
    const unsigned short* p0 = yp4 + ((size_t)tm.x * CAP_TOK + tm.y) * OUTD + q * 8;
    const unsigned short* p1 = yp4 + ((size_t)tm.z * CAP_TOK + tm.w) * OUTD + q * 8;
    float y0[8] = {0,0,0,0,0,0,0,0};
    float y1[8] = {0,0,0,0,0,0,0,0};
    #pragma unroll
    for (int h = 0; h < 4; ++h) {
        u16x8 a = __builtin_nontemporal_load((const u16x8*)(p0 + h * hstep));
        u16x8 b = __builtin_nontemporal_load((const u16x8*)(p1 + h * hstep));
        #pragma unroll
        for (int j = 0; j < 8; ++j) { y0[j] += bf2f(a[j]); y1[j] += bf2f(b[j]); }
    }
    const float* c0 = &b2[tm.x * OUTD + q * 8];
    const float* c1 = &b2[tm.z * OUTD + q * 8];
    f32x4 r0, r1;
    #pragma unroll
    for (int j = 0; j < 4; ++j) {
        r0[j] = g.x * (y0[j] + c0[j]) + g.y * (y1[j] + c1[j]);
        r1[j] = g.x * (y0[4 + j] + c0[4 + j]) + g.y * (y1[4 + j] + c1[4 + j]);
    }
    float* op = &out[(size_t)t * OUTD + q * 8];
    __builtin_nontemporal_store(r0, (f32x4*)op);
    __builtin_nontemporal_store(r1, (f32x4*)(op + 4));
}

// ---------------------------------------------------------------- launch
extern "C" void kernel_launch(void* const* d_in, const int* in_sizes, int n_in,
                              void* d_out, int out_size, void* d_ws, size_t ws_size,
                              hipStream_t stream) {
    const float* x  = (const float*)d_in[0];
    const float* Wg = (const float*)d_in[1];
    const float* bg = (const float*)d_in[2];
    const float* W1 = (const float*)d_in[3];
    const float* b1 = (const float*)d_in[4];
    const float* W2 = (const float*)d_in[5];
    const float* b2 = (const float*)d_in[6];
    float* out = (float*)d_out;

    char* ws = (char*)d_ws;                                    // all offsets 1KB-aligned
    int*            cnt    = (int*)ws;                         // 32 B
    int*            btok   = (int*)(ws + 1024);                // 256 KB
    int*            tokmap = (int*)(ws + 263168);              // 128 KB
    float*          gmap   = (float*)(ws + 394240);            // 64 KB
    unsigned short* xg     = (unsigned short*)(ws + 459776);   // 13.5 MB
    unsigned short* w1s    = (unsigned short*)(ws + 14615552); // 9.44 MB
    unsigned short* w2s    = (unsigned short*)(ws + 24052736); // 9.44 MB
    unsigned short* yp4    = (unsigned short*)(ws + 33489920); // 56.6 MB -> end ~90 MB

    // W1: K=DIM, N=HID -> NT=48, KT=24 ; W2: K=HID, N=OUTD -> NT=12, KT=96
    hipLaunchKernelGGL(swizzle_kernel, dim3(NEXP * 48 * 24 * 64 / 256), dim3(256), 0, stream,
                       W1, w1s, DIM, HID, 48, 24, cnt);
    hipLaunchKernelGGL(swizzle_kernel, dim3(NEXP * 12 * 96 * 64 / 256), dim3(256), 0, stream,
                       W2, w2s, HID, OUTD, 12, 96, (int*)nullptr);
    hipLaunchKernelGGL(router_kernel, dim3(N_TOK / 256), dim3(256), 0, stream,
                       x, Wg, bg, cnt, btok, tokmap, gmap);
    hipLaunchKernelGGL(gather_kernel, dim3(CAP_MT, NEXP), dim3(256), 0, stream,
                       x, cnt, btok, xg);
    hipLaunchKernelGGL(expert_kernel, dim3(NEXP * 4 * CAP_TB), dim3(512), 0, stream,
                       xg, w1s, w2s, b1, cnt, yp4);
    hipLaunchKernelGGL(reduce_kernel, dim3(N_TOK * 48 / 256), dim3(256), 0, stream,
                       yp4, tokmap, gmap, b2, out);
}